// Round 7
// baseline (523.446 us; speedup 1.0000x reference)
//
#include <hip/hip_runtime.h>
#include <math.h>

#define BM 128
#define BN 128
#define BK 64

typedef _Float16 f16x8 __attribute__((ext_vector_type(8)));
typedef __attribute__((ext_vector_type(4))) float f32x4;

typedef const __attribute__((address_space(1))) void* gas_ptr;
typedef __attribute__((address_space(3))) void* las_ptr;

enum { OP_NONE = 0, OP_BIAS_GELU = 1, OP_BIAS = 2, OP_SCALE_MASK = 3 };

__device__ __forceinline__ unsigned short f2h(float f) {
    _Float16 h = (_Float16)f;  // RTNE
    unsigned short u;
    __builtin_memcpy(&u, &h, 2);
    return u;
}
__device__ __forceinline__ float h2f(unsigned short u) {
    _Float16 h;
    __builtin_memcpy(&h, &u, 2);
    return (float)h;
}

// tanh-form GELU via sigmoid: ~7 VALU instrs vs ~50 for libm erff.
// Confirmed: absmax stays 0.03125 with this approximation.
__device__ __forceinline__ float fast_gelu(float x) {
    float x2 = x * x;
    float p  = x * (-1.5957691216f - 0.0713548164f * x2);  // = -2u
    float t  = __expf(p);                                  // e^{-2u}
    return x * __builtin_amdgcn_rcpf(1.0f + t);            // x * sigma(2u)
}

// C = A @ B, B given transposed (BT is [N][K] row-major). A [M][K], C [M][N].
// fp16 in/out, fp32 accumulate. BK=64 XOR-swizzled global_load_lds staging
// (0 bank conflicts). 16x16x32 MFMA (R3 A/B: 32x32x16 frag reads cost 1.26e7
// bank conflicts/dispatch, +21% dur -- 16x16 fr/quad is the conflict-free
// pattern). j-INNERMOST epilogue (R2/R4-validated: WRITE_SIZE at exact ideal,
// MLP 114->108 us). Body byte-identical since R4; clones (gemm_pair,
// gemm_btT) are SEPARATE kernels so these hot instantiations keep their
// codegen (rule #19; R5 regression, R6 fix confirmed).
// __launch_bounds__(256, 4): 4 blocks/CU co-residency hides prologue/epilogue
// and the per-K-step barrier drain; beat the 1-block/CU 256^2 8-phase at
// K=1024 (R1/R2).
template <int EPI, bool CAUSAL_K, bool TRI, bool REVM>
__global__ __launch_bounds__(256, 4) void gemm_bt(
    const unsigned short* __restrict__ A,
    const unsigned short* __restrict__ BT,
    unsigned short* __restrict__ Cw,
    const float* __restrict__ bias0,
    const float* __restrict__ bias1,
    const float* __restrict__ bias2,
    int M, int N, int K,
    long long sA, long long sB, long long sC,
    float scale)
{
    __shared__ __align__(16) unsigned short As[BM * BK];
    __shared__ __align__(16) unsigned short Bs[BN * BK];

    const int tid  = threadIdx.x;
    const int wave = tid >> 6;
    const int lane = tid & 63;

    int bm, bn, z;
    if (TRI) {
        // unrank t -> (i, j), j <= i, t = i(i+1)/2 + j
        const int t = blockIdx.x;
        int i = (int)((sqrtf(8.0f * t + 1.0f) - 1.0f) * 0.5f);
        while ((i + 1) * (i + 2) / 2 <= t) i++;
        while (i * (i + 1) / 2 > t) i--;
        const int j = t - i * (i + 1) / 2;
        bm = i * BM;
        bn = j * BN;
        z  = blockIdx.y;
    } else {
        bm = (REVM ? (gridDim.x - 1 - blockIdx.x) : blockIdx.x) * BM;
        bn = blockIdx.y * BN;
        z  = blockIdx.z;
    }

    const unsigned short* Ab = A  + (long long)z * sA;
    const unsigned short* Bb = BT + (long long)z * sB;
    unsigned short*       Cb = Cw + (long long)z * sC;
    const float* bias = nullptr;
    if (EPI == OP_BIAS || EPI == OP_BIAS_GELU)
        bias = (z == 0) ? bias0 : (z == 1) ? bias1 : bias2;

    const int wm = (wave >> 1) * 64;  // wave's 64x64 quadrant
    const int wn = (wave & 1) * 64;

    f32x4 acc[4][4];
    #pragma unroll
    for (int i = 0; i < 4; i++)
        #pragma unroll
        for (int j = 0; j < 4; j++)
            acc[i][j] = (f32x4){0.f, 0.f, 0.f, 0.f};

    int Keff = K;
    if (CAUSAL_K) {
        int kl = bm + BM;
        Keff = kl < K ? kl : K;
    }

    const int srow = lane >> 3;                          // row within 8-row slab
    const int gchw = ((lane & 7) ^ (srow & 7)) * 8;      // swizzled chunk, halfwords
    const int fr   = lane & 15;
    const int quad = lane >> 4;

    // per-lane global staging pointers; advance by BK per iter
    const unsigned short* pA = Ab + (long long)(bm + wave * 32 + srow) * K + gchw;
    const unsigned short* pB = Bb + (long long)(bn + wave * 32 + srow) * K + gchw;
    const long long rstep = 8ll * K;  // 8 rows between the 4 slabs of a wave

    for (int k0 = 0; k0 < Keff; k0 += BK) {
        #pragma unroll
        for (int s = 0; s < 4; ++s) {
            const int t = wave * 4 + s;
            __builtin_amdgcn_global_load_lds((gas_ptr)(const void*)(pA + s * rstep),
                                             (las_ptr)(void*)&As[t * 512 + lane * 8],
                                             16, 0, 0);
            __builtin_amdgcn_global_load_lds((gas_ptr)(const void*)(pB + s * rstep),
                                             (las_ptr)(void*)&Bs[t * 512 + lane * 8],
                                             16, 0, 0);
        }
        pA += BK;
        pB += BK;
        __syncthreads();  // drains vmcnt -> staged data visible

        #pragma unroll
        for (int kk = 0; kk < 2; ++kk) {
            f16x8 fa[4], fb[4];
            #pragma unroll
            for (int i = 0; i < 4; i++) {
                const int row  = wm + i * 16 + fr;
                const int slot = row * 8 + ((kk * 4 + quad) ^ (fr & 7));
                fa[i] = *(const f16x8*)&As[slot * 8];
            }
            #pragma unroll
            for (int j = 0; j < 4; j++) {
                const int row  = wn + j * 16 + fr;
                const int slot = row * 8 + ((kk * 4 + quad) ^ (fr & 7));
                fb[j] = *(const f16x8*)&Bs[slot * 8];
            }
            #pragma unroll
            for (int i = 0; i < 4; i++)
                #pragma unroll
                for (int j = 0; j < 4; j++)
                    acc[i][j] = __builtin_amdgcn_mfma_f32_16x16x32_f16(
                        fa[i], fb[j], acc[i][j], 0, 0, 0);
        }
        __syncthreads();  // protect LDS before next stage overwrites
    }

    // epilogue: C/D layout col=lane&15, row=(lane>>4)*4+reg  [m89/m91]
    // j INNERMOST: per (i,r), lanes cover cols [wn, wn+64) in 4 consecutive
    // 32B stores -> each 128B L2 line fully dirtied immediately.
    const int er = quad;
    const int ec = fr;
    float bj[4];
    if (EPI == OP_BIAS || EPI == OP_BIAS_GELU) {
        #pragma unroll
        for (int j = 0; j < 4; j++) bj[j] = bias[bn + wn + j * 16 + ec];
    }
    #pragma unroll
    for (int i = 0; i < 4; i++) {
        #pragma unroll
        for (int r = 0; r < 4; r++) {
            const int row = bm + wm + i * 16 + er * 4 + r;
            #pragma unroll
            for (int j = 0; j < 4; j++) {
                const int col = bn + wn + j * 16 + ec;
                float v = acc[i][j][r];
                if (EPI == OP_BIAS_GELU) {
                    v = fast_gelu(v + bj[j]);
                } else if (EPI == OP_BIAS) {
                    v += bj[j];
                } else if (EPI == OP_SCALE_MASK) {
                    v *= scale;
                    if (col > row) v = 0.f;
                }
                Cb[(long long)row * N + col] = f2h(v);
            }
        }
    }
}

// R7: v-head of MLP2 with TRANSPOSED output: vT[batch][channel][token] =
// (h_v @ W2v + b2v)^T. Replaces the separate 64MB-traffic transpose64
// dispatch. Key: in the m89/m91 C/D layout, acc[i][j][r] r=0..3 are 4
// CONSECUTIVE rows (tokens) at one column (channel) -> a contiguous ushort4
// run of vT. Per (j, i-loop): each vT 128B line is completed within 4
// consecutive store instructions (R2/R4 line-complete discipline).
// Standalone clone so hot gemm_bt codegen is untouched (rule #19).
__global__ __launch_bounds__(256, 4) void gemm_btT(
    const unsigned short* __restrict__ A,   // h_v [M][K]
    const unsigned short* __restrict__ BT,  // W2vT [N][K]
    unsigned short* __restrict__ vT,        // [NB][N][T]
    const float* __restrict__ bias,         // b2v [N]
    int N, int K, int T)
{
    __shared__ __align__(16) unsigned short As[BM * BK];
    __shared__ __align__(16) unsigned short Bs[BN * BK];

    const int tid  = threadIdx.x;
    const int wave = tid >> 6;
    const int lane = tid & 63;

    const int bm = blockIdx.x * BM;
    const int bn = blockIdx.y * BN;

    const int wm = (wave >> 1) * 64;
    const int wn = (wave & 1) * 64;

    f32x4 acc[4][4];
    #pragma unroll
    for (int i = 0; i < 4; i++)
        #pragma unroll
        for (int j = 0; j < 4; j++)
            acc[i][j] = (f32x4){0.f, 0.f, 0.f, 0.f};

    const int srow = lane >> 3;
    const int gchw = ((lane & 7) ^ (srow & 7)) * 8;
    const int fr   = lane & 15;
    const int quad = lane >> 4;

    const unsigned short* pA = A  + (long long)(bm + wave * 32 + srow) * K + gchw;
    const unsigned short* pB = BT + (long long)(bn + wave * 32 + srow) * K + gchw;
    const long long rstep = 8ll * K;

    for (int k0 = 0; k0 < K; k0 += BK) {
        #pragma unroll
        for (int s = 0; s < 4; ++s) {
            const int t = wave * 4 + s;
            __builtin_amdgcn_global_load_lds((gas_ptr)(const void*)(pA + s * rstep),
                                             (las_ptr)(void*)&As[t * 512 + lane * 8],
                                             16, 0, 0);
            __builtin_amdgcn_global_load_lds((gas_ptr)(const void*)(pB + s * rstep),
                                             (las_ptr)(void*)&Bs[t * 512 + lane * 8],
                                             16, 0, 0);
        }
        pA += BK;
        pB += BK;
        __syncthreads();

        #pragma unroll
        for (int kk = 0; kk < 2; ++kk) {
            f16x8 fa[4], fb[4];
            #pragma unroll
            for (int i = 0; i < 4; i++) {
                const int row  = wm + i * 16 + fr;
                const int slot = row * 8 + ((kk * 4 + quad) ^ (fr & 7));
                fa[i] = *(const f16x8*)&As[slot * 8];
            }
            #pragma unroll
            for (int j = 0; j < 4; j++) {
                const int row  = wn + j * 16 + fr;
                const int slot = row * 8 + ((kk * 4 + quad) ^ (fr & 7));
                fb[j] = *(const f16x8*)&Bs[slot * 8];
            }
            #pragma unroll
            for (int i = 0; i < 4; i++)
                #pragma unroll
                for (int j = 0; j < 4; j++)
                    acc[i][j] = __builtin_amdgcn_mfma_f32_16x16x32_f16(
                        fa[i], fb[j], acc[i][j], 0, 0, 0);
        }
        __syncthreads();
    }

    // transposed epilogue: tok = row, vT row = col. acc[i][j][0..3] are 4
    // consecutive tokens at one channel -> one ushort4 store each.
    const int er = quad;
    const int ec = fr;
    const int batch = bm >> 11;                       // 2048 tokens per batch
    unsigned short* vTb = vT + (long long)batch * ((long long)N * T);
    const int tokbase = (bm & 2047) + wm;
    #pragma unroll
    for (int j = 0; j < 4; j++) {
        const int col = bn + wn + j * 16 + ec;
        const float bj = bias[col];
        #pragma unroll
        for (int i = 0; i < 4; i++) {
            const int tok = tokbase + i * 16 + er * 4;
            ushort4 o;
            o.x = f2h(acc[i][j][0] + bj);
            o.y = f2h(acc[i][j][1] + bj);
            o.z = f2h(acc[i][j][2] + bj);
            o.w = f2h(acc[i][j][3] + bj);
            *(ushort4*)&vTb[(long long)col * T + tok] = o;
        }
    }
}

// out_pre = scores @ v, causal K (Keff = bm+BM), complementary-pair balanced:
// block bx does bm-tiles {bx, 2*gridDim.x-1-bx} -> constant 17*128 K-rows per
// block regardless of block->CU assignment (R5: -17 us vs unbalanced).
// Separate kernel so the hot gemm_bt instantiations keep R4 codegen (rule #19).
__global__ __launch_bounds__(256, 4) void gemm_pair(
    const unsigned short* __restrict__ A,
    const unsigned short* __restrict__ BT,
    unsigned short* __restrict__ Cw,
    int M, int N, int K,
    long long sA, long long sB, long long sC)
{
    __shared__ __align__(16) unsigned short As[BM * BK];
    __shared__ __align__(16) unsigned short Bs[BN * BK];

    const int tid  = threadIdx.x;
    const int wave = tid >> 6;
    const int lane = tid & 63;

    const int wm = (wave >> 1) * 64;
    const int wn = (wave & 1) * 64;

    const int srow = lane >> 3;
    const int gchw = ((lane & 7) ^ (srow & 7)) * 8;
    const int fr   = lane & 15;
    const int quad = lane >> 4;

    const int z  = blockIdx.z;
    const int bn = blockIdx.y * BN;
    const unsigned short* Ab = A  + (long long)z * sA;
    const unsigned short* Bb = BT + (long long)z * sB;
    unsigned short*       Cb = Cw + (long long)z * sC;

    #pragma unroll 1
    for (int half = 0; half < 2; ++half) {
        const int mb = half ? (2 * (int)gridDim.x - 1 - (int)blockIdx.x)
                            : (int)blockIdx.x;
        const int bm = mb * BM;

        f32x4 acc[4][4];
        #pragma unroll
        for (int i = 0; i < 4; i++)
            #pragma unroll
            for (int j = 0; j < 4; j++)
                acc[i][j] = (f32x4){0.f, 0.f, 0.f, 0.f};

        int Keff = bm + BM;
        if (Keff > K) Keff = K;

        const unsigned short* pA = Ab + (long long)(bm + wave * 32 + srow) * K + gchw;
        const unsigned short* pB = Bb + (long long)(bn + wave * 32 + srow) * K + gchw;
        const long long rstep = 8ll * K;

        for (int k0 = 0; k0 < Keff; k0 += BK) {
            #pragma unroll
            for (int s = 0; s < 4; ++s) {
                const int t = wave * 4 + s;
                __builtin_amdgcn_global_load_lds((gas_ptr)(const void*)(pA + s * rstep),
                                                 (las_ptr)(void*)&As[t * 512 + lane * 8],
                                                 16, 0, 0);
                __builtin_amdgcn_global_load_lds((gas_ptr)(const void*)(pB + s * rstep),
                                                 (las_ptr)(void*)&Bs[t * 512 + lane * 8],
                                                 16, 0, 0);
            }
            pA += BK;
            pB += BK;
            __syncthreads();

            #pragma unroll
            for (int kk = 0; kk < 2; ++kk) {
                f16x8 fa[4], fb[4];
                #pragma unroll
                for (int i = 0; i < 4; i++) {
                    const int row  = wm + i * 16 + fr;
                    const int slot = row * 8 + ((kk * 4 + quad) ^ (fr & 7));
                    fa[i] = *(const f16x8*)&As[slot * 8];
                }
                #pragma unroll
                for (int j = 0; j < 4; j++) {
                    const int row  = wn + j * 16 + fr;
                    const int slot = row * 8 + ((kk * 4 + quad) ^ (fr & 7));
                    fb[j] = *(const f16x8*)&Bs[slot * 8];
                }
                #pragma unroll
                for (int i = 0; i < 4; i++)
                    #pragma unroll
                    for (int j = 0; j < 4; j++)
                        acc[i][j] = __builtin_amdgcn_mfma_f32_16x16x32_f16(
                            fa[i], fb[j], acc[i][j], 0, 0, 0);
            }
            __syncthreads();
        }

        const int er = quad;
        const int ec = fr;
        #pragma unroll
        for (int i = 0; i < 4; i++) {
            #pragma unroll
            for (int r = 0; r < 4; r++) {
                const int row = bm + wm + i * 16 + er * 4 + r;
                #pragma unroll
                for (int j = 0; j < 4; j++) {
                    const int col = bn + wn + j * 16 + ec;
                    Cb[(long long)row * N + col] = f2h(acc[i][j][r]);
                }
            }
        }
        // LDS reuse across halves race-free: last ds_reads precede the final
        // __syncthreads of the K-loop; epilogue touches no LDS.
    }
}

// fp32 -> fp16 elementwise (n divisible by 1024)
__global__ __launch_bounds__(256) void cvt_f32_f16(
    const float4* __restrict__ in, ushort4* __restrict__ out)
{
    int i = blockIdx.x * 256 + threadIdx.x;
    float4 f = in[i];
    ushort4 o;
    o.x = f2h(f.x); o.y = f2h(f.y); o.z = f2h(f.z); o.w = f2h(f.w);
    out[i] = o;
}

// all six weight matrices: fp32 -> fp16 transposed. 64x64 tiles with float4
// (16B) loads and ushort4 (8B) stores (R6).
__global__ __launch_bounds__(256) void wprep64(
    const float* __restrict__ s0, const float* __restrict__ s1,
    const float* __restrict__ s2, const float* __restrict__ s3,
    const float* __restrict__ s4, const float* __restrict__ s5,
    unsigned short* __restrict__ W1T, unsigned short* __restrict__ W2T)
{
    const int C = 1024;
    const int z = blockIdx.z;
    const float* in = (z == 0) ? s0 : (z == 1) ? s1 : (z == 2) ? s2
                    : (z == 3) ? s3 : (z == 4) ? s4 : s5;
    unsigned short* out = (z < 3) ? (W1T + (long long)z * C * C)
                                  : (W2T + (long long)(z - 3) * C * C);
    __shared__ unsigned short tile[64][68];  // stride 68 shorts (8B-aligned)
    const int bx = blockIdx.x * 64;  // col base
    const int by = blockIdx.y * 64;  // row base
    const int tid = threadIdx.x;
    const int rsub = tid >> 4;        // 0..15
    const int c4   = (tid & 15) * 4;  // 0,4,..,60
    #pragma unroll
    for (int it = 0; it < 4; it++) {
        const int r = it * 16 + rsub;
        float4 v = *(const float4*)&in[(long long)(by + r) * C + (bx + c4)];
        tile[r][c4]     = f2h(v.x);
        tile[r][c4 + 1] = f2h(v.y);
        tile[r][c4 + 2] = f2h(v.z);
        tile[r][c4 + 3] = f2h(v.w);
    }
    __syncthreads();
    #pragma unroll
    for (int it = 0; it < 4; it++) {
        const int cc = it * 16 + rsub;  // out row = in col
        ushort4 v;
        v.x = tile[c4][cc];
        v.y = tile[c4 + 1][cc];
        v.z = tile[c4 + 2][cc];
        v.w = tile[c4 + 3][cc];
        *(ushort4*)&out[(long long)(bx + cc) * C + (by + c4)] = v;
    }
}

// wave-per-row layernorm (R6). 4 rows per 256-thread block; each lane holds
// 16 elems; pure __shfl_xor butterfly reduce -- no LDS, no barriers.
__global__ __launch_bounds__(256) void layernorm_w(
    const unsigned short* __restrict__ X,
    const float* __restrict__ W,
    const float* __restrict__ Bv,
    float* __restrict__ Y)
{
    const int wave = threadIdx.x >> 6;
    const int lane = threadIdx.x & 63;
    const long long row = (long long)blockIdx.x * 4 + wave;
    const unsigned short* xr = X + row * 1024;
    float f[16];
    float s = 0.f, ss = 0.f;
    #pragma unroll
    for (int t = 0; t < 4; t++) {
        ushort4 u = *(const ushort4*)&xr[lane * 4 + t * 256];
        float a = h2f(u.x), b = h2f(u.y), c = h2f(u.z), d = h2f(u.w);
        f[t * 4 + 0] = a; f[t * 4 + 1] = b; f[t * 4 + 2] = c; f[t * 4 + 3] = d;
        s  += a + b + c + d;
        ss += a * a + b * b + c * c + d * d;
    }
    #pragma unroll
    for (int off = 32; off >= 1; off >>= 1) {
        s  += __shfl_xor(s, off);
        ss += __shfl_xor(ss, off);
    }
    const float mu  = s * (1.f / 1024.f);
    const float var = ss * (1.f / 1024.f) - mu * mu;
    const float rs  = rsqrtf(var + 1e-5f);
    #pragma unroll
    for (int t = 0; t < 4; t++) {
        float4 w4 = *(const float4*)&W[lane * 4 + t * 256];
        float4 b4 = *(const float4*)&Bv[lane * 4 + t * 256];
        float4 o;
        o.x = (f[t * 4 + 0] - mu) * rs * w4.x + b4.x;
        o.y = (f[t * 4 + 1] - mu) * rs * w4.y + b4.y;
        o.z = (f[t * 4 + 2] - mu) * rs * w4.z + b4.z;
        o.w = (f[t * 4 + 3] - mu) * rs * w4.w + b4.w;
        *(float4*)&Y[row * 1024 + lane * 4 + t * 256] = o;
    }
}

extern "C" void kernel_launch(void* const* d_in, const int* in_sizes, int n_in,
                              void* d_out, int out_size, void* d_ws, size_t ws_size,
                              hipStream_t stream)
{
    const int C  = 1024;
    const int T  = 2048;
    const int NB = 8;
    const int MT = NB * T;  // 16384 rows

    const float* x = (const float*)d_in[0];
    const float* W1q = (const float*)d_in[1];
    const float* b1q = (const float*)d_in[2];
    const float* W2q = (const float*)d_in[3];
    const float* b2q = (const float*)d_in[4];
    const float* W1k = (const float*)d_in[5];
    const float* b1k = (const float*)d_in[6];
    const float* W2k = (const float*)d_in[7];
    const float* b2k = (const float*)d_in[8];
    const float* W1v = (const float*)d_in[9];
    const float* b1v = (const float*)d_in[10];
    const float* W2v = (const float*)d_in[11];
    const float* b2v = (const float*)d_in[12];
    const float* lnw = (const float*)d_in[13];
    const float* lnb = (const float*)d_in[14];

    char* wsp = (char*)d_ws;
    auto take = [&](size_t bytes) {
        char* p = wsp;
        wsp += (bytes + 255) & ~(size_t)255;
        return p;
    };

    const size_t MATE = (size_t)MT * C;  // elements per [16384][1024] matrix

    unsigned short* W1T  = (unsigned short*)take((size_t)3 * C * C * 2);
    unsigned short* W2T  = (unsigned short*)take((size_t)3 * C * C * 2);
    unsigned short* xb   = (unsigned short*)take(MATE * 2);
    unsigned short* qkv  = (unsigned short*)take(3 * MATE * 2);  // q,k (v unused)
    unsigned short* hreg = (unsigned short*)take(3 * MATE * 2);  // h; later scb+opre
    unsigned short* qb   = qkv;
    unsigned short* kb   = qkv + MATE;
    unsigned short* vT   = xb;                               // xb dead after MLP1
    unsigned short* scb  = hreg;                             // 8*T*T = 2*MATE elems
    unsigned short* opre = hreg + (size_t)NB * T * T;        // MATE elems — exact fit

    // x: fp32 -> fp16
    cvt_f32_f16<<<dim3(MT * C / 1024, 1, 1), dim3(256, 1, 1), 0, stream>>>(
        (const float4*)x, (ushort4*)xb);

    // all weights: fp32 -> fp16 transposed, one dispatch (64x64 vectorized)
    wprep64<<<dim3(C / 64, C / 64, 6), dim3(256, 1, 1), 0, stream>>>(
        W1q, W1k, W1v, W2q, W2k, W2v, W1T, W2T);

    dim3 blk(256, 1, 1);

    // MLP GEMM1 (z = head): h_z = GELU(x @ W1_z + b1_z)   grid (M,N,z)
    gemm_bt<OP_BIAS_GELU, false, false, false><<<dim3(MT / BM, C / BN, 3), blk, 0, stream>>>(
        xb, W1T, hreg, b1q, b1k, b1v, MT, C, C,
        0, (long long)C * C, (long long)MATE, 1.f);

    // MLP GEMM2 q,k heads: {q,k}_z = h_z @ W2_z + b2_z
    gemm_bt<OP_BIAS, false, false, false><<<dim3(MT / BM, C / BN, 2), blk, 0, stream>>>(
        hreg, W2T, qkv, b2q, b2k, nullptr, MT, C, C,
        (long long)MATE, (long long)C * C, (long long)MATE, 1.f);

    // MLP GEMM2 v head, transposed output: vT[b][channel][token] (R7 —
    // replaces the separate transpose64 dispatch and its 64MB of traffic)
    gemm_btT<<<dim3(MT / BM, C / BN, 1), blk, 0, stream>>>(
        hreg + 2 * MATE, W2T + 2 * (size_t)C * C, vT, b2v, C, C, T);

    // scores = tril(q @ k^T) / sqrt(C*T); packed lower-triangle grid
    float inv_scale = 1.0f / sqrtf((float)C * (float)T);
    gemm_bt<OP_SCALE_MASK, false, true, false><<<dim3(136, NB, 1), blk, 0, stream>>>(
        qb, kb, scb, nullptr, nullptr, nullptr, T, T, C,
        (long long)T * C, (long long)T * C, (long long)T * T, inv_scale);

    // out_pre = scores @ v; complementary-pair balanced (constant per-block work)
    gemm_pair<<<dim3(T / BM / 2, C / BN, NB), blk, 0, stream>>>(
        scb, vT, opre, T, C, T,
        (long long)T * T, (long long)T * C, (long long)T * C);

    layernorm_w<<<dim3(MT / 4, 1, 1), dim3(256, 1, 1), 0, stream>>>(
        opre, lnw, lnb, (float*)d_out);
}

// Round 8
// 516.480 us; speedup vs baseline: 1.0135x; 1.0135x over previous
//
#include <hip/hip_runtime.h>
#include <math.h>

#define BM 128
#define BN 128
#define BK 64

typedef _Float16 f16x8 __attribute__((ext_vector_type(8)));
typedef __attribute__((ext_vector_type(4))) float f32x4;

typedef const __attribute__((address_space(1))) void* gas_ptr;
typedef __attribute__((address_space(3))) void* las_ptr;

enum { OP_NONE = 0, OP_BIAS_GELU = 1, OP_BIAS = 2, OP_SCALE_MASK = 3 };

__device__ __forceinline__ unsigned short f2h(float f) {
    _Float16 h = (_Float16)f;  // RTNE
    unsigned short u;
    __builtin_memcpy(&u, &h, 2);
    return u;
}
__device__ __forceinline__ float h2f(unsigned short u) {
    _Float16 h;
    __builtin_memcpy(&h, &u, 2);
    return (float)h;
}

// tanh-form GELU via sigmoid: ~7 VALU instrs vs ~50 for libm erff.
// Confirmed: absmax stays 0.03125 with this approximation.
__device__ __forceinline__ float fast_gelu(float x) {
    float x2 = x * x;
    float p  = x * (-1.5957691216f - 0.0713548164f * x2);  // = -2u
    float t  = __expf(p);                                  // e^{-2u}
    return x * __builtin_amdgcn_rcpf(1.0f + t);            // x * sigma(2u)
}

// C = A @ B, B given transposed (BT is [N][K] row-major). A [M][K], C [M][N].
// fp16 in/out, fp32 accumulate. BK=64 XOR-swizzled global_load_lds staging
// (0 bank conflicts). 16x16x32 MFMA (R3: 32x32x16 frag reads cost 1.26e7 bank
// conflicts, +21%). j-INNERMOST epilogue (R2/R4: WRITE_SIZE at exact ideal).
// Body byte-identical since R4; all variants (gemm_mlp2, gemm_pair) are
// SEPARATE kernels and the OP_BIAS instantiation is kept alive explicitly so
// the co-compilation set matches R7 (rule #19; R5 regression, R6 fix).
template <int EPI, bool CAUSAL_K, bool TRI, bool REVM>
__global__ __launch_bounds__(256, 4) void gemm_bt(
    const unsigned short* __restrict__ A,
    const unsigned short* __restrict__ BT,
    unsigned short* __restrict__ Cw,
    const float* __restrict__ bias0,
    const float* __restrict__ bias1,
    const float* __restrict__ bias2,
    int M, int N, int K,
    long long sA, long long sB, long long sC,
    float scale)
{
    __shared__ __align__(16) unsigned short As[BM * BK];
    __shared__ __align__(16) unsigned short Bs[BN * BK];

    const int tid  = threadIdx.x;
    const int wave = tid >> 6;
    const int lane = tid & 63;

    int bm, bn, z;
    if (TRI) {
        // unrank t -> (i, j), j <= i, t = i(i+1)/2 + j
        const int t = blockIdx.x;
        int i = (int)((sqrtf(8.0f * t + 1.0f) - 1.0f) * 0.5f);
        while ((i + 1) * (i + 2) / 2 <= t) i++;
        while (i * (i + 1) / 2 > t) i--;
        const int j = t - i * (i + 1) / 2;
        bm = i * BM;
        bn = j * BN;
        z  = blockIdx.y;
    } else {
        bm = (REVM ? (gridDim.x - 1 - blockIdx.x) : blockIdx.x) * BM;
        bn = blockIdx.y * BN;
        z  = blockIdx.z;
    }

    const unsigned short* Ab = A  + (long long)z * sA;
    const unsigned short* Bb = BT + (long long)z * sB;
    unsigned short*       Cb = Cw + (long long)z * sC;
    const float* bias = nullptr;
    if (EPI == OP_BIAS || EPI == OP_BIAS_GELU)
        bias = (z == 0) ? bias0 : (z == 1) ? bias1 : bias2;

    const int wm = (wave >> 1) * 64;  // wave's 64x64 quadrant
    const int wn = (wave & 1) * 64;

    f32x4 acc[4][4];
    #pragma unroll
    for (int i = 0; i < 4; i++)
        #pragma unroll
        for (int j = 0; j < 4; j++)
            acc[i][j] = (f32x4){0.f, 0.f, 0.f, 0.f};

    int Keff = K;
    if (CAUSAL_K) {
        int kl = bm + BM;
        Keff = kl < K ? kl : K;
    }

    const int srow = lane >> 3;                          // row within 8-row slab
    const int gchw = ((lane & 7) ^ (srow & 7)) * 8;      // swizzled chunk, halfwords
    const int fr   = lane & 15;
    const int quad = lane >> 4;

    // per-lane global staging pointers; advance by BK per iter
    const unsigned short* pA = Ab + (long long)(bm + wave * 32 + srow) * K + gchw;
    const unsigned short* pB = Bb + (long long)(bn + wave * 32 + srow) * K + gchw;
    const long long rstep = 8ll * K;  // 8 rows between the 4 slabs of a wave

    for (int k0 = 0; k0 < Keff; k0 += BK) {
        #pragma unroll
        for (int s = 0; s < 4; ++s) {
            const int t = wave * 4 + s;
            __builtin_amdgcn_global_load_lds((gas_ptr)(const void*)(pA + s * rstep),
                                             (las_ptr)(void*)&As[t * 512 + lane * 8],
                                             16, 0, 0);
            __builtin_amdgcn_global_load_lds((gas_ptr)(const void*)(pB + s * rstep),
                                             (las_ptr)(void*)&Bs[t * 512 + lane * 8],
                                             16, 0, 0);
        }
        pA += BK;
        pB += BK;
        __syncthreads();  // drains vmcnt -> staged data visible

        #pragma unroll
        for (int kk = 0; kk < 2; ++kk) {
            f16x8 fa[4], fb[4];
            #pragma unroll
            for (int i = 0; i < 4; i++) {
                const int row  = wm + i * 16 + fr;
                const int slot = row * 8 + ((kk * 4 + quad) ^ (fr & 7));
                fa[i] = *(const f16x8*)&As[slot * 8];
            }
            #pragma unroll
            for (int j = 0; j < 4; j++) {
                const int row  = wn + j * 16 + fr;
                const int slot = row * 8 + ((kk * 4 + quad) ^ (fr & 7));
                fb[j] = *(const f16x8*)&Bs[slot * 8];
            }
            #pragma unroll
            for (int i = 0; i < 4; i++)
                #pragma unroll
                for (int j = 0; j < 4; j++)
                    acc[i][j] = __builtin_amdgcn_mfma_f32_16x16x32_f16(
                        fa[i], fb[j], acc[i][j], 0, 0, 0);
        }
        __syncthreads();  // protect LDS before next stage overwrites
    }

    // epilogue: C/D layout col=lane&15, row=(lane>>4)*4+reg  [m89/m91]
    // j INNERMOST: per (i,r), lanes cover cols [wn, wn+64) in 4 consecutive
    // 32B stores -> each 128B L2 line fully dirtied immediately.
    const int er = quad;
    const int ec = fr;
    float bj[4];
    if (EPI == OP_BIAS || EPI == OP_BIAS_GELU) {
        #pragma unroll
        for (int j = 0; j < 4; j++) bj[j] = bias[bn + wn + j * 16 + ec];
    }
    #pragma unroll
    for (int i = 0; i < 4; i++) {
        #pragma unroll
        for (int r = 0; r < 4; r++) {
            const int row = bm + wm + i * 16 + er * 4 + r;
            #pragma unroll
            for (int j = 0; j < 4; j++) {
                const int col = bn + wn + j * 16 + ec;
                float v = acc[i][j][r];
                if (EPI == OP_BIAS_GELU) {
                    v = fast_gelu(v + bj[j]);
                } else if (EPI == OP_BIAS) {
                    v += bj[j];
                } else if (EPI == OP_SCALE_MASK) {
                    v *= scale;
                    if (col > row) v = 0.f;
                }
                Cb[(long long)row * N + col] = f2h(v);
            }
        }
    }
}

// Keep the OP_BIAS instantiation compiled even though the merged gemm_mlp2
// replaces its dispatch: preserves the exact template co-compilation set of
// R7 so MLP1/scores codegen cannot shift (rule #19).
template __global__ void gemm_bt<OP_BIAS, false, false, false>(
    const unsigned short*, const unsigned short*, unsigned short*,
    const float*, const float*, const float*, int, int, int,
    long long, long long, long long, float);

// R8: all three MLP2 heads in ONE dispatch (3072 blocks = 3 exact
// co-residency rounds, one less boundary). z=0,1 (q,k): normal j-inner
// epilogue. z=2 (v): R7's transposed-vT epilogue (validated, absmax
// unchanged). Standalone clone: hot gemm_bt codegen untouched.
__global__ __launch_bounds__(256, 4) void gemm_mlp2(
    const unsigned short* __restrict__ A,    // h [3][M][K] contiguous
    const unsigned short* __restrict__ BT,   // W2T [3][N][K] contiguous
    unsigned short* __restrict__ Cqk,        // q,k [2][M][N]
    unsigned short* __restrict__ vT,         // [NB][N][T]
    const float* __restrict__ b2q,
    const float* __restrict__ b2k,
    const float* __restrict__ b2v,
    int M, int N, int K, int T)
{
    __shared__ __align__(16) unsigned short As[BM * BK];
    __shared__ __align__(16) unsigned short Bs[BN * BK];

    const int tid  = threadIdx.x;
    const int wave = tid >> 6;
    const int lane = tid & 63;

    const int bm = blockIdx.x * BM;
    const int bn = blockIdx.y * BN;
    const int z  = blockIdx.z;

    const unsigned short* Ab = A  + (long long)z * M * K;
    const unsigned short* Bb = BT + (long long)z * N * K;
    const float* bias = (z == 0) ? b2q : (z == 1) ? b2k : b2v;

    const int wm = (wave >> 1) * 64;
    const int wn = (wave & 1) * 64;

    f32x4 acc[4][4];
    #pragma unroll
    for (int i = 0; i < 4; i++)
        #pragma unroll
        for (int j = 0; j < 4; j++)
            acc[i][j] = (f32x4){0.f, 0.f, 0.f, 0.f};

    const int srow = lane >> 3;
    const int gchw = ((lane & 7) ^ (srow & 7)) * 8;
    const int fr   = lane & 15;
    const int quad = lane >> 4;

    const unsigned short* pA = Ab + (long long)(bm + wave * 32 + srow) * K + gchw;
    const unsigned short* pB = Bb + (long long)(bn + wave * 32 + srow) * K + gchw;
    const long long rstep = 8ll * K;

    for (int k0 = 0; k0 < K; k0 += BK) {
        #pragma unroll
        for (int s = 0; s < 4; ++s) {
            const int t = wave * 4 + s;
            __builtin_amdgcn_global_load_lds((gas_ptr)(const void*)(pA + s * rstep),
                                             (las_ptr)(void*)&As[t * 512 + lane * 8],
                                             16, 0, 0);
            __builtin_amdgcn_global_load_lds((gas_ptr)(const void*)(pB + s * rstep),
                                             (las_ptr)(void*)&Bs[t * 512 + lane * 8],
                                             16, 0, 0);
        }
        pA += BK;
        pB += BK;
        __syncthreads();

        #pragma unroll
        for (int kk = 0; kk < 2; ++kk) {
            f16x8 fa[4], fb[4];
            #pragma unroll
            for (int i = 0; i < 4; i++) {
                const int row  = wm + i * 16 + fr;
                const int slot = row * 8 + ((kk * 4 + quad) ^ (fr & 7));
                fa[i] = *(const f16x8*)&As[slot * 8];
            }
            #pragma unroll
            for (int j = 0; j < 4; j++) {
                const int row  = wn + j * 16 + fr;
                const int slot = row * 8 + ((kk * 4 + quad) ^ (fr & 7));
                fb[j] = *(const f16x8*)&Bs[slot * 8];
            }
            #pragma unroll
            for (int i = 0; i < 4; i++)
                #pragma unroll
                for (int j = 0; j < 4; j++)
                    acc[i][j] = __builtin_amdgcn_mfma_f32_16x16x32_f16(
                        fa[i], fb[j], acc[i][j], 0, 0, 0);
        }
        __syncthreads();
    }

    const int er = quad;
    const int ec = fr;
    if (z < 2) {
        // normal epilogue (j innermost, line-complete)
        unsigned short* Cb = Cqk + (long long)z * M * N;
        float bj[4];
        #pragma unroll
        for (int j = 0; j < 4; j++) bj[j] = bias[bn + wn + j * 16 + ec];
        #pragma unroll
        for (int i = 0; i < 4; i++) {
            #pragma unroll
            for (int r = 0; r < 4; r++) {
                const int row = bm + wm + i * 16 + er * 4 + r;
                #pragma unroll
                for (int j = 0; j < 4; j++) {
                    const int col = bn + wn + j * 16 + ec;
                    Cb[(long long)row * N + col] = f2h(acc[i][j][r] + bj[j]);
                }
            }
        }
    } else {
        // transposed epilogue: vT[batch][channel][token]; acc[i][j][0..3] are
        // 4 consecutive tokens at one channel -> one ushort4 store each (R7).
        const int batch = bm >> 11;                  // 2048 tokens per batch
        unsigned short* vTb = vT + (long long)batch * ((long long)N * T);
        const int tokbase = (bm & 2047) + wm;
        #pragma unroll
        for (int j = 0; j < 4; j++) {
            const int col = bn + wn + j * 16 + ec;
            const float bj = bias[col];
            #pragma unroll
            for (int i = 0; i < 4; i++) {
                const int tok = tokbase + i * 16 + er * 4;
                ushort4 o;
                o.x = f2h(acc[i][j][0] + bj);
                o.y = f2h(acc[i][j][1] + bj);
                o.z = f2h(acc[i][j][2] + bj);
                o.w = f2h(acc[i][j][3] + bj);
                *(ushort4*)&vTb[(long long)col * T + tok] = o;
            }
        }
    }
}

// out_pre = scores @ v, causal K (Keff = bm+BM), complementary-pair balanced:
// block bx does bm-tiles {bx, 2*gridDim.x-1-bx} -> constant 17*128 K-rows per
// block regardless of block->CU assignment (R5: -17 us vs unbalanced).
__global__ __launch_bounds__(256, 4) void gemm_pair(
    const unsigned short* __restrict__ A,
    const unsigned short* __restrict__ BT,
    unsigned short* __restrict__ Cw,
    int M, int N, int K,
    long long sA, long long sB, long long sC)
{
    __shared__ __align__(16) unsigned short As[BM * BK];
    __shared__ __align__(16) unsigned short Bs[BN * BK];

    const int tid  = threadIdx.x;
    const int wave = tid >> 6;
    const int lane = tid & 63;

    const int wm = (wave >> 1) * 64;
    const int wn = (wave & 1) * 64;

    const int srow = lane >> 3;
    const int gchw = ((lane & 7) ^ (srow & 7)) * 8;
    const int fr   = lane & 15;
    const int quad = lane >> 4;

    const int z  = blockIdx.z;
    const int bn = blockIdx.y * BN;
    const unsigned short* Ab = A  + (long long)z * sA;
    const unsigned short* Bb = BT + (long long)z * sB;
    unsigned short*       Cb = Cw + (long long)z * sC;

    #pragma unroll 1
    for (int half = 0; half < 2; ++half) {
        const int mb = half ? (2 * (int)gridDim.x - 1 - (int)blockIdx.x)
                            : (int)blockIdx.x;
        const int bm = mb * BM;

        f32x4 acc[4][4];
        #pragma unroll
        for (int i = 0; i < 4; i++)
            #pragma unroll
            for (int j = 0; j < 4; j++)
                acc[i][j] = (f32x4){0.f, 0.f, 0.f, 0.f};

        int Keff = bm + BM;
        if (Keff > K) Keff = K;

        const unsigned short* pA = Ab + (long long)(bm + wave * 32 + srow) * K + gchw;
        const unsigned short* pB = Bb + (long long)(bn + wave * 32 + srow) * K + gchw;
        const long long rstep = 8ll * K;

        for (int k0 = 0; k0 < Keff; k0 += BK) {
            #pragma unroll
            for (int s = 0; s < 4; ++s) {
                const int t = wave * 4 + s;
                __builtin_amdgcn_global_load_lds((gas_ptr)(const void*)(pA + s * rstep),
                                                 (las_ptr)(void*)&As[t * 512 + lane * 8],
                                                 16, 0, 0);
                __builtin_amdgcn_global_load_lds((gas_ptr)(const void*)(pB + s * rstep),
                                                 (las_ptr)(void*)&Bs[t * 512 + lane * 8],
                                                 16, 0, 0);
            }
            pA += BK;
            pB += BK;
            __syncthreads();

            #pragma unroll
            for (int kk = 0; kk < 2; ++kk) {
                f16x8 fa[4], fb[4];
                #pragma unroll
                for (int i = 0; i < 4; i++) {
                    const int row  = wm + i * 16 + fr;
                    const int slot = row * 8 + ((kk * 4 + quad) ^ (fr & 7));
                    fa[i] = *(const f16x8*)&As[slot * 8];
                }
                #pragma unroll
                for (int j = 0; j < 4; j++) {
                    const int row  = wn + j * 16 + fr;
                    const int slot = row * 8 + ((kk * 4 + quad) ^ (fr & 7));
                    fb[j] = *(const f16x8*)&Bs[slot * 8];
                }
                #pragma unroll
                for (int i = 0; i < 4; i++)
                    #pragma unroll
                    for (int j = 0; j < 4; j++)
                        acc[i][j] = __builtin_amdgcn_mfma_f32_16x16x32_f16(
                            fa[i], fb[j], acc[i][j], 0, 0, 0);
            }
            __syncthreads();
        }

        const int er = quad;
        const int ec = fr;
        #pragma unroll
        for (int i = 0; i < 4; i++) {
            #pragma unroll
            for (int r = 0; r < 4; r++) {
                const int row = bm + wm + i * 16 + er * 4 + r;
                #pragma unroll
                for (int j = 0; j < 4; j++) {
                    const int col = bn + wn + j * 16 + ec;
                    Cb[(long long)row * N + col] = f2h(acc[i][j][r]);
                }
            }
        }
        // LDS reuse across halves race-free: last ds_reads precede the final
        // __syncthreads of the K-loop; epilogue touches no LDS.
    }
}

// R8: cvt + weight-prep merged into one dispatch (block-index branch; the
// two block families never cross a barrier together -- cvt blocks return
// before the wprep path's __syncthreads).
__global__ __launch_bounds__(256) void prep(
    const float4* __restrict__ x4, ushort4* __restrict__ xb4, int ncvt,
    const float* __restrict__ s0, const float* __restrict__ s1,
    const float* __restrict__ s2, const float* __restrict__ s3,
    const float* __restrict__ s4, const float* __restrict__ s5,
    unsigned short* __restrict__ W1T, unsigned short* __restrict__ W2T)
{
    const int bx = blockIdx.x;
    const int tid = threadIdx.x;
    if (bx < ncvt) {
        int i = bx * 256 + tid;
        float4 f = x4[i];
        ushort4 o;
        o.x = f2h(f.x); o.y = f2h(f.y); o.z = f2h(f.z); o.w = f2h(f.w);
        xb4[i] = o;
        return;
    }
    const int C = 1024;
    const int b2 = bx - ncvt;
    const int z = b2 >> 8;            // 256 tiles (16x16 of 64x64) per matrix
    const int rem = b2 & 255;
    const float* in = (z == 0) ? s0 : (z == 1) ? s1 : (z == 2) ? s2
                    : (z == 3) ? s3 : (z == 4) ? s4 : s5;
    unsigned short* out = (z < 3) ? (W1T + (long long)z * C * C)
                                  : (W2T + (long long)(z - 3) * C * C);
    __shared__ unsigned short tile[64][68];  // stride 68 shorts (8B-aligned)
    const int bxt = (rem & 15) * 64;  // col base
    const int byt = (rem >> 4) * 64;  // row base
    const int rsub = tid >> 4;        // 0..15
    const int c4   = (tid & 15) * 4;  // 0,4,..,60
    #pragma unroll
    for (int it = 0; it < 4; it++) {
        const int r = it * 16 + rsub;
        float4 v = *(const float4*)&in[(long long)(byt + r) * C + (bxt + c4)];
        tile[r][c4]     = f2h(v.x);
        tile[r][c4 + 1] = f2h(v.y);
        tile[r][c4 + 2] = f2h(v.z);
        tile[r][c4 + 3] = f2h(v.w);
    }
    __syncthreads();
    #pragma unroll
    for (int it = 0; it < 4; it++) {
        const int cc = it * 16 + rsub;  // out row = in col
        ushort4 v;
        v.x = tile[c4][cc];
        v.y = tile[c4 + 1][cc];
        v.z = tile[c4 + 2][cc];
        v.w = tile[c4 + 3][cc];
        *(ushort4*)&out[(long long)(bxt + cc) * C + (byt + c4)] = v;
    }
}

// wave-per-row layernorm (R6). 4 rows per 256-thread block; each lane holds
// 16 elems; pure __shfl_xor butterfly reduce -- no LDS, no barriers.
__global__ __launch_bounds__(256) void layernorm_w(
    const unsigned short* __restrict__ X,
    const float* __restrict__ W,
    const float* __restrict__ Bv,
    float* __restrict__ Y)
{
    const int wave = threadIdx.x >> 6;
    const int lane = threadIdx.x & 63;
    const long long row = (long long)blockIdx.x * 4 + wave;
    const unsigned short* xr = X + row * 1024;
    float f[16];
    float s = 0.f, ss = 0.f;
    #pragma unroll
    for (int t = 0; t < 4; t++) {
        ushort4 u = *(const ushort4*)&xr[lane * 4 + t * 256];
        float a = h2f(u.x), b = h2f(u.y), c = h2f(u.z), d = h2f(u.w);
        f[t * 4 + 0] = a; f[t * 4 + 1] = b; f[t * 4 + 2] = c; f[t * 4 + 3] = d;
        s  += a + b + c + d;
        ss += a * a + b * b + c * c + d * d;
    }
    #pragma unroll
    for (int off = 32; off >= 1; off >>= 1) {
        s  += __shfl_xor(s, off);
        ss += __shfl_xor(ss, off);
    }
    const float mu  = s * (1.f / 1024.f);
    const float var = ss * (1.f / 1024.f) - mu * mu;
    const float rs  = rsqrtf(var + 1e-5f);
    #pragma unroll
    for (int t = 0; t < 4; t++) {
        float4 w4 = *(const float4*)&W[lane * 4 + t * 256];
        float4 b4 = *(const float4*)&Bv[lane * 4 + t * 256];
        float4 o;
        o.x = (f[t * 4 + 0] - mu) * rs * w4.x + b4.x;
        o.y = (f[t * 4 + 1] - mu) * rs * w4.y + b4.y;
        o.z = (f[t * 4 + 2] - mu) * rs * w4.z + b4.z;
        o.w = (f[t * 4 + 3] - mu) * rs * w4.w + b4.w;
        *(float4*)&Y[row * 1024 + lane * 4 + t * 256] = o;
    }
}

extern "C" void kernel_launch(void* const* d_in, const int* in_sizes, int n_in,
                              void* d_out, int out_size, void* d_ws, size_t ws_size,
                              hipStream_t stream)
{
    const int C  = 1024;
    const int T  = 2048;
    const int NB = 8;
    const int MT = NB * T;  // 16384 rows

    const float* x = (const float*)d_in[0];
    const float* W1q = (const float*)d_in[1];
    const float* b1q = (const float*)d_in[2];
    const float* W2q = (const float*)d_in[3];
    const float* b2q = (const float*)d_in[4];
    const float* W1k = (const float*)d_in[5];
    const float* b1k = (const float*)d_in[6];
    const float* W2k = (const float*)d_in[7];
    const float* b2k = (const float*)d_in[8];
    const float* W1v = (const float*)d_in[9];
    const float* b1v = (const float*)d_in[10];
    const float* W2v = (const float*)d_in[11];
    const float* b2v = (const float*)d_in[12];
    const float* lnw = (const float*)d_in[13];
    const float* lnb = (const float*)d_in[14];

    char* wsp = (char*)d_ws;
    auto take = [&](size_t bytes) {
        char* p = wsp;
        wsp += (bytes + 255) & ~(size_t)255;
        return p;
    };

    const size_t MATE = (size_t)MT * C;  // elements per [16384][1024] matrix

    unsigned short* W1T  = (unsigned short*)take((size_t)3 * C * C * 2);
    unsigned short* W2T  = (unsigned short*)take((size_t)3 * C * C * 2);
    unsigned short* xb   = (unsigned short*)take(MATE * 2);
    unsigned short* qkv  = (unsigned short*)take(3 * MATE * 2);  // q,k
    unsigned short* hreg = (unsigned short*)take(3 * MATE * 2);  // h; later scb+opre
    unsigned short* qb   = qkv;
    unsigned short* kb   = qkv + MATE;
    unsigned short* vT   = xb;                               // xb dead after MLP1
    unsigned short* scb  = hreg;                             // 8*T*T = 2*MATE elems
    unsigned short* opre = hreg + (size_t)NB * T * T;        // MATE elems — exact fit

    dim3 blk(256, 1, 1);

    // x fp32->fp16 AND all-weight transpose prep, one dispatch
    const int ncvt = MT * C / 1024;  // 16384 cvt blocks
    prep<<<dim3(ncvt + 1536, 1, 1), blk, 0, stream>>>(
        (const float4*)x, (ushort4*)xb, ncvt,
        W1q, W1k, W1v, W2q, W2k, W2v, W1T, W2T);

    // MLP GEMM1 (z = head): h_z = GELU(x @ W1_z + b1_z)   grid (M,N,z)
    gemm_bt<OP_BIAS_GELU, false, false, false><<<dim3(MT / BM, C / BN, 3), blk, 0, stream>>>(
        xb, W1T, hreg, b1q, b1k, b1v, MT, C, C,
        0, (long long)C * C, (long long)MATE, 1.f);

    // MLP GEMM2, all heads in one dispatch: q,k normal; v transposed to vT
    gemm_mlp2<<<dim3(MT / BM, C / BN, 3), blk, 0, stream>>>(
        hreg, W2T, qkv, vT, b2q, b2k, b2v, MT, C, C, T);

    // scores = tril(q @ k^T) / sqrt(C*T); packed lower-triangle grid
    float inv_scale = 1.0f / sqrtf((float)C * (float)T);
    gemm_bt<OP_SCALE_MASK, false, true, false><<<dim3(136, NB, 1), blk, 0, stream>>>(
        qb, kb, scb, nullptr, nullptr, nullptr, T, T, C,
        (long long)T * C, (long long)T * C, (long long)T * T, inv_scale);

    // out_pre = scores @ v; complementary-pair balanced (constant per-block work)
    gemm_pair<<<dim3(T / BM / 2, C / BN, NB), blk, 0, stream>>>(
        scb, vT, opre, T, C, T,
        (long long)T * T, (long long)T * C, (long long)T * C);

    layernorm_w<<<dim3(MT / 4, 1, 1), dim3(256, 1, 1), 0, stream>>>(
        opre, lnw, lnb, (float*)d_out);
}